// Round 6
// baseline (687.325 us; speedup 1.0000x reference)
//
#include <hip/hip_runtime.h>
#include <hip/hip_bf16.h>
#include <math.h>

#define B_    500
#define T_    100
#define I_    700
#define HALF_ 350
#define H_    512
#define O_    20
#define M_    (B_*T_)     // 50000
#define BH_   (B_*H_)     // 256000
#define KP_   352         // padded K per phase (W1 pad @350-351, W2 shifted by 2)
#define ASTR_ 712         // A LDS row stride in shorts (1424B: 16B-aligned, 2-way banks)
#define SCS_  20          // scanD h-row stride in shorts (40B: 8B-aligned, spread banks)
#define SCPH_ (128*SCS_)  // scanD phase plane
#define NB_   12500       // out_loss blocks

#define START_T  10
#define CODING_T 10
#define REMAIN_T 5

typedef __attribute__((ext_vector_type(8))) short short8v;
typedef __attribute__((ext_vector_type(8))) unsigned short ushort8v;
typedef __attribute__((ext_vector_type(4))) float f32x4;

__device__ __forceinline__ float sigmoidf_(float x) {
  return 1.0f / (1.0f + expf(-x));
}

// HW packed cvt: D[15:0]=bf16(lo), D[31:16]=bf16(hi), RTNE
__device__ __forceinline__ unsigned cvtpk(float lo, float hi) {
  unsigned r;
  asm("v_cvt_pk_bf16_f32 %0, %1, %2" : "=v"(r) : "v"(lo), "v"(hi));
  return r;
}

__device__ __forceinline__ unsigned short f2bf(float f) {
  unsigned u = __float_as_uint(f);
  u = (u + 0x7fffu + ((u >> 16) & 1u)) >> 16;   // RTNE
  return (unsigned short)u;
}

// ---------- convert weights fp32 -> padded bf16 Wb[2][512][352] ----------
// phase 0: kk<350 -> W1[kk], else 0      (A shorts 0..351   = input floats 0..351)
// phase 1: kk>=2  -> W2[kk-2], else 0    (A shorts 352..703 = input floats 348..699)
__global__ __launch_bounds__(256) void convert_w(
    const float* __restrict__ W1, const float* __restrict__ W2,
    unsigned short* __restrict__ wb)
{
  const int idx = blockIdx.x * 256 + threadIdx.x;  // 8-elem chunk; 45056 total
  const int ph  = idx / (H_ * (KP_ / 8));
  const int rem = idx % (H_ * (KP_ / 8));
  const int h   = rem / (KP_ / 8);
  const int cc  = (rem % (KP_ / 8)) * 8;
  ushort8v v;
#pragma unroll
  for (int j = 0; j < 8; ++j) {
    const int kk = cc + j;
    float f;
    if (ph == 0) f = (kk < HALF_) ? W1[(size_t)h * HALF_ + kk] : 0.0f;
    else         f = (kk >= 2)    ? W2[(size_t)h * HALF_ + kk - 2] : 0.0f;
    v[j] = f2bf(f);
  }
  *reinterpret_cast<ushort8v*>(wb + (((size_t)ph * H_ + h) * KP_) + cc) = v;
}

// ---------- fused: per-(b,htile) drive GEMM (t-chunked) + LIF scan ----------
__global__ __launch_bounds__(256, 4) void fused_drive_scan(
    const float* __restrict__ input, const unsigned short* __restrict__ Wb,
    const float* __restrict__ v_init, const float* __restrict__ tau_n,
    const float* __restrict__ tau_m, unsigned char* __restrict__ spikes)
{
  __shared__ __align__(16) unsigned short As[16 * ASTR_];       // 22784 B
  __shared__ __align__(16) unsigned short scanD[2 * SCPH_];     // 10240 B

  const int tid  = threadIdx.x;
  const int lane = tid & 63;
  const int w    = tid >> 6;

  // XCD-chunked swizzle: 4 h-tiles of each b on one XCD (input L2 reuse).
  const int id    = blockIdx.x;                 // 0..1999 (2000 % 8 == 0)
  const int work  = (id & 7) * 250 + (id >> 3);
  const int htile = work & 3;
  const int b     = work >> 2;
  const int h0    = htile * 128;

  // B fragment addressing (direct global; Wb is L2-resident)
  const int brow = h0 + w * 32 + (lane & 15);
  const int kcS  = (lane >> 4) * 8;
  const unsigned short* bp0 = Wb + (size_t)brow * KP_ + kcS;
  const unsigned short* bp1 = Wb + (size_t)(brow + 16) * KP_ + kcS;
  const int arow = lane & 15;
  const int toff = (lane >> 4) * 4;

  // ---- staging setup (upper 128 threads) ----
  const int su = tid - 128;            // 0..127 for upper
  const int sr = su >> 3;              // A row 0..15
  const int sc = (su & 7) * 4;         // col chunk base (floats/shorts)
  unsigned short* sDst = As + sr * ASTR_ + sc;

  // ---- scan state (lower 128 threads), persistent across chunks ----
  float beta1 = 0.f, beta2 = 0.f, alpha = 0.f, ob1 = 0.f, ob2 = 0.f, oa = 0.f;
  float d1 = 0.f, d2 = 0.f, v = 0.f, s = 0.f;
  unsigned char* sp = spikes + (size_t)b * H_ + h0 + tid;  // lower only

  if (tid < 128) {
    const int hg = h0 + tid;
    beta1 = sigmoidf_(tau_n[hg]);
    beta2 = sigmoidf_(tau_n[H_ + hg]);
    alpha = sigmoidf_(tau_m[hg]);
    ob1 = 1.0f - beta1; ob2 = 1.0f - beta2; oa = 1.0f - alpha;
    v = v_init[(size_t)b * H_ + hg];
  } else {
    // stage chunk 0
    const int t = sr;                  // c = 0
    const float* src = input + ((size_t)b * T_ + t) * I_;
#pragma unroll
    for (int q = 0; q < 11; ++q) {
      const float4 x0 = *(const float4*)(src + sc + q * 32);
      const float4 x1 = *(const float4*)(src + 348 + sc + q * 32);
      const uint2 p0 = {cvtpk(x0.x, x0.y), cvtpk(x0.z, x0.w)};
      const uint2 p1 = {cvtpk(x1.x, x1.y), cvtpk(x1.z, x1.w)};
      *(uint2*)(sDst + q * 32) = p0;
      *(uint2*)(sDst + 352 + q * 32) = p1;
    }
  }
  __syncthreads();

#pragma unroll 1
  for (int c = 0; c < 7; ++c) {
    // ---- barrier-free K loop: 22 steps over both phases ----
    f32x4 acc[2][2];
#pragma unroll
    for (int ph = 0; ph < 2; ++ph)
#pragma unroll
      for (int j = 0; j < 2; ++j) acc[ph][j] = f32x4{0.f, 0.f, 0.f, 0.f};

    short8v bC0 = *reinterpret_cast<const short8v*>(bp0);
    short8v bC1 = *reinterpret_cast<const short8v*>(bp1);
    short8v bN0 = *reinterpret_cast<const short8v*>(bp0 + 32);
    short8v bN1 = *reinterpret_cast<const short8v*>(bp1 + 32);

#pragma unroll
    for (int k = 0; k < 22; ++k) {
      const int ph = (k >= 11) ? 1 : 0;
      const short8v a =
          *reinterpret_cast<const short8v*>(As + arow * ASTR_ + k * 32 + kcS);
      acc[ph][0] = __builtin_amdgcn_mfma_f32_16x16x32_bf16(a, bC0, acc[ph][0], 0, 0, 0);
      acc[ph][1] = __builtin_amdgcn_mfma_f32_16x16x32_bf16(a, bC1, acc[ph][1], 0, 0, 0);
      bC0 = bN0; bC1 = bN1;
      if (k < 20) {
        const int kn  = k + 2;
        const int phn = (kn >= 11) ? 1 : 0;
        const size_t bo = (size_t)phn * H_ * KP_ + (kn - phn * 11) * 32;
        bN0 = *reinterpret_cast<const short8v*>(bp0 + bo);
        bN1 = *reinterpret_cast<const short8v*>(bp1 + bo);
      }
    }

    // ---- dump acc -> scanD [ph][h][t_local] ----
#pragma unroll
    for (int ph = 0; ph < 2; ++ph)
#pragma unroll
      for (int j = 0; j < 2; ++j) {
        const int h = w * 32 + j * 16 + (lane & 15);
        const uint2 pk = {cvtpk(acc[ph][j][0], acc[ph][j][1]),
                          cvtpk(acc[ph][j][2], acc[ph][j][3])};
        *(uint2*)(scanD + ph * SCPH_ + h * SCS_ + toff) = pk;
      }
    __syncthreads();

    // ---- lower: scan(c)  ||  upper: stage(c+1) ----
    if (tid < 128) {
      const int nt = (c == 6) ? 4 : 16;
      const unsigned short* r1 = scanD + tid * SCS_;
      const unsigned short* r2 = scanD + SCPH_ + tid * SCS_;
#pragma unroll
      for (int g = 0; g < 4; ++g) {
        if (g * 4 >= nt) break;
        const uint2 x1 = *(const uint2*)(r1 + g * 4);
        const uint2 x2 = *(const uint2*)(r2 + g * 4);
        const unsigned u1[2] = {x1.x, x1.y};
        const unsigned u2[2] = {x2.x, x2.y};
#pragma unroll
        for (int j = 0; j < 4; ++j) {
          const unsigned w1u = u1[j >> 1], w2u = u2[j >> 1];
          const float f1 = (j & 1) ? __uint_as_float(w1u & 0xffff0000u)
                                   : __uint_as_float(w1u << 16);
          const float f2 = (j & 1) ? __uint_as_float(w2u & 0xffff0000u)
                                   : __uint_as_float(w2u << 16);
          d1 = beta1 * d1 + ob1 * f1;
          d2 = beta2 * d2 + ob2 * f2;
          v = alpha * v + oa * (d1 + d2) - s;   // V_TH = 1
          s = (v > 1.0f) ? 1.0f : 0.0f;
          sp[(size_t)(c * 16 + g * 4 + j) * BH_] = (unsigned char)s;
        }
      }
    } else if (c < 6) {
      const int t = (c + 1) * 16 + sr;
      if (t < T_) {
        const float* src = input + ((size_t)b * T_ + t) * I_;
#pragma unroll
        for (int q = 0; q < 11; ++q) {
          const float4 x0 = *(const float4*)(src + sc + q * 32);
          const float4 x1 = *(const float4*)(src + 348 + sc + q * 32);
          const uint2 p0 = {cvtpk(x0.x, x0.y), cvtpk(x0.z, x0.w)};
          const uint2 p1 = {cvtpk(x1.x, x1.y), cvtpk(x1.z, x1.w)};
          *(uint2*)(sDst + q * 32) = p0;
          *(uint2*)(sDst + 352 + q * 32) = p1;
        }
      } else {
        const uint2 z = {0, 0};
#pragma unroll
        for (int q = 0; q < 11; ++q) {
          *(uint2*)(sDst + q * 32) = z;
          *(uint2*)(sDst + 352 + q * 32) = z;
        }
      }
    }
    __syncthreads();
  }
}

// ---------- fused output GEMM + loss partials (wave per (b,t)) ----------
__global__ __launch_bounds__(256) void out_loss(
    const unsigned char* __restrict__ spikes, const float* __restrict__ Wout,
    const float* __restrict__ bout, const int* __restrict__ target,
    float* __restrict__ oh, float* __restrict__ partials)
{
  const int lane = threadIdx.x & 63;
  const int widx = threadIdx.x >> 6;
  const int bt = blockIdx.x * 4 + widx;
  const int b = bt / T_, t = bt - b * T_;

  const unsigned char* srow = spikes + ((size_t)t * B_ + b) * H_;
  const uint2 sv = *(const uint2*)(srow + lane * 8);

  float acc[O_];
#pragma unroll
  for (int o = 0; o < O_; ++o) acc[o] = 0.0f;

#pragma unroll
  for (int j = 0; j < 8; ++j) {
    const unsigned sb = ((j < 4) ? (sv.x >> (8 * j)) : (sv.y >> (8 * (j - 4)))) & 255u;
    if (sb) {
      const int hh = lane * 8 + j;
#pragma unroll
      for (int o = 0; o < O_; ++o) acc[o] += Wout[o * H_ + hh];
    }
  }
#pragma unroll
  for (int o = 0; o < O_; ++o) {
#pragma unroll
    for (int off = 32; off > 0; off >>= 1) acc[o] += __shfl_down(acc[o], off);
  }

  __shared__ float sl[4], sc[4];
  if (lane == 0) {
    float r[O_];
    float* orow = oh + ((size_t)b * T_ + t) * O_;
#pragma unroll
    for (int o = 0; o < O_; ++o) { r[o] = acc[o] + bout[o]; orow[o] = r[o]; }

    float lossc = 0.0f, corr = 0.0f;
    const bool maskv = (t > START_T) && (((t - START_T) % (CODING_T + REMAIN_T)) > REMAIN_T);
    if (maskv) {
      float m = r[0];
#pragma unroll
      for (int o = 1; o < O_; ++o) m = fmaxf(m, r[o]);
      const int tgt = target[(size_t)b * T_ + t];
      float e[O_], S = 0.0f, etgt = 0.0f;
#pragma unroll
      for (int o = 0; o < O_; ++o) {
        e[o] = expf(r[o] - m);
        S += e[o];
        etgt = (o == tgt) ? e[o] : etgt;
      }
      const float inv = 1.0f / S;
      const float pm = inv;            // max(p) = exp(0)/S
      float S2 = 0.0f;
#pragma unroll
      for (int o = 0; o < O_; ++o) S2 += expf(e[o] * inv - pm);
      const float lse = pm + logf(S2);
      lossc = (lse - etgt * inv) * (1.0f / (float)B_);
      int pred = 0;
      float bm = r[0];
#pragma unroll
      for (int o = 1; o < O_; ++o) { if (r[o] > bm) { bm = r[o]; pred = o; } }
      corr = (pred == tgt) ? 1.0f : 0.0f;
    }
    sl[widx] = lossc; sc[widx] = corr;
  }
  __syncthreads();
  if (threadIdx.x == 0) {
    partials[blockIdx.x]       = sl[0] + sl[1] + sl[2] + sl[3];
    partials[NB_ + blockIdx.x] = sc[0] + sc[1] + sc[2] + sc[3];
  }
}

__global__ __launch_bounds__(256) void loss_final(
    const float* __restrict__ partials, float* __restrict__ out, float samples)
{
  float a = 0.0f, c = 0.0f;
  for (int i = threadIdx.x; i < NB_; i += 256) { a += partials[i]; c += partials[NB_ + i]; }
  __shared__ float sl[256], sc[256];
  sl[threadIdx.x] = a; sc[threadIdx.x] = c;
  __syncthreads();
  for (int s = 128; s > 0; s >>= 1) {
    if (threadIdx.x < s) {
      sl[threadIdx.x] += sl[threadIdx.x + s];
      sc[threadIdx.x] += sc[threadIdx.x + s];
    }
    __syncthreads();
  }
  if (threadIdx.x == 0) {
    out[0] = sl[0];
    out[1 + (size_t)M_ * O_] = sc[0];
    out[2 + (size_t)M_ * O_] = samples;
  }
}

extern "C" void kernel_launch(void* const* d_in, const int* in_sizes, int n_in,
                              void* d_out, int out_size, void* d_ws, size_t ws_size,
                              hipStream_t stream) {
  const float* input  = (const float*)d_in[0];
  const int*   target = (const int*)d_in[1];
  const float* v_init = (const float*)d_in[2];
  const float* W1     = (const float*)d_in[3];
  const float* W2     = (const float*)d_in[4];
  const float* tau_n  = (const float*)d_in[5];
  const float* tau_m  = (const float*)d_in[6];
  const float* Wout   = (const float*)d_in[7];
  const float* bout   = (const float*)d_in[8];
  float* out = (float*)d_out;
  float* oh  = out + 1;

  // ws layout: Wb[2*512*352 bf16] spikes[T*BH u8] partials[2*NB_ f32]
  unsigned short* Wb = (unsigned short*)d_ws;
  unsigned char* spikes = (unsigned char*)(Wb + (size_t)2 * H_ * KP_);
  float* partials = (float*)(spikes + (size_t)T_ * BH_);

  const dim3 blk(256);

  hipLaunchKernelGGL(convert_w, dim3((2 * H_ * KP_ / 8) / 256), blk, 0, stream,
                     W1, W2, Wb);

  hipLaunchKernelGGL(fused_drive_scan, dim3(2000), blk, 0, stream,
                     input, Wb, v_init, tau_n, tau_m, spikes);

  hipLaunchKernelGGL(out_loss, dim3(NB_), blk, 0, stream,
                     spikes, Wout, bout, target, oh, partials);

  int mcount = 0;
  for (int t = 0; t < T_; ++t)
    if (t > START_T && ((t - START_T) % (CODING_T + REMAIN_T)) > REMAIN_T) mcount++;
  hipLaunchKernelGGL(loss_final, dim3(1), blk, 0, stream, partials,
                     out, (float)(mcount * B_));
}

// Round 7
// 209.594 us; speedup vs baseline: 3.2793x; 3.2793x over previous
//
#include <hip/hip_runtime.h>
#include <hip/hip_bf16.h>
#include <math.h>

#define B_    500
#define T_    100
#define I_    700
#define HALF_ 350
#define H_    512
#define O_    20
#define M_    (B_*T_)     // 50000
#define BH_   (B_*H_)     // 256000
#define TP_   112         // T padded to 7*16
#define KP_   352         // padded K per phase
#define ASTR_ 40          // A LDS row stride shorts (80B: keeps b128 16B-aligned)
#define DRS_  116         // dr LDS t-stride shorts (232B: b64-aligned rows)
#define NB_   12500       // out_loss blocks

#define START_T  10
#define CODING_T 10
#define REMAIN_T 5

typedef __attribute__((ext_vector_type(8))) short short8v;
typedef __attribute__((ext_vector_type(8))) unsigned short ushort8v;
typedef __attribute__((ext_vector_type(4))) float f32x4;

__device__ __forceinline__ float sigmoidf_(float x) {
  return 1.0f / (1.0f + expf(-x));
}

// HW packed cvt: D[15:0]=bf16(lo), D[31:16]=bf16(hi), RTNE
__device__ __forceinline__ unsigned cvtpk(float lo, float hi) {
  unsigned r;
  asm("v_cvt_pk_bf16_f32 %0, %1, %2" : "=v"(r) : "v"(lo), "v"(hi));
  return r;
}

__device__ __forceinline__ unsigned short f2bf(float f) {
  unsigned u = __float_as_uint(f);
  u = (u + 0x7fffu + ((u >> 16) & 1u)) >> 16;   // RTNE
  return (unsigned short)u;
}

// ---------- convert weights fp32 -> padded bf16 Wb[2][512][352] ----------
// phase 0: kk<350 -> W1[kk], else 0      (A cols 0..351)
// phase 1: kk>=2  -> W2[kk-2], else 0    (A cols 348..699; 16B-aligned base)
__global__ __launch_bounds__(256) void convert_w(
    const float* __restrict__ W1, const float* __restrict__ W2,
    unsigned short* __restrict__ wb)
{
  const int idx = blockIdx.x * 256 + threadIdx.x;  // 8-elem chunk; 45056 total
  const int ph  = idx / (H_ * (KP_ / 8));
  const int rem = idx % (H_ * (KP_ / 8));
  const int h   = rem / (KP_ / 8);
  const int cc  = (rem % (KP_ / 8)) * 8;
  ushort8v v;
#pragma unroll
  for (int j = 0; j < 8; ++j) {
    const int kk = cc + j;
    float f;
    if (ph == 0) f = (kk < HALF_) ? W1[(size_t)h * HALF_ + kk] : 0.0f;
    else         f = (kk >= 2)    ? W2[(size_t)h * HALF_ + kk - 2] : 0.0f;
    v[j] = f2bf(f);
  }
  *reinterpret_cast<ushort8v*>(wb + (((size_t)ph * H_ + h) * KP_) + cc) = v;
}

// ---------- fused: drive GEMM (per-b) + in-LDS LIF scan -> spikes ----------
__global__ __launch_bounds__(256) void fused_drive_scan(
    const float* __restrict__ input, const unsigned short* __restrict__ Wb,
    const float* __restrict__ v_init, const float* __restrict__ tau_n,
    const float* __restrict__ tau_m, unsigned char* __restrict__ spikes)
{
  __shared__ __align__(16) unsigned short As[2 * TP_ * ASTR_];  // 17920 B
  __shared__ __align__(16) unsigned short d1s[128 * DRS_];      // 29696 B
  __shared__ __align__(16) unsigned short d2s[128 * DRS_];      // 29696 B

  const int tid  = threadIdx.x;
  const int lane = tid & 63;
  const int w    = tid >> 6;

  // XCD-chunked swizzle: 4 h-tiles of each b on one XCD (input L2 reuse).
  const int id    = blockIdx.x;                 // 0..1999 (2000 % 8 == 0)
  const int work  = (id & 7) * 250 + (id >> 3);
  const int htile = work & 3;
  const int b     = work >> 2;
  const int h0    = htile * 128;

  // A staging: thread tau<224 -> row t = tau>>1, half = tau&1 (16 cols)
  const int stT    = tid >> 1;
  const int stHalf = tid & 1;
  const bool stLd  = (tid < 224) && (stT < T_);
  const bool stZr  = (tid < 224) && (stT >= T_);
  const float* aBase = input + ((size_t)b * T_ + (stT < T_ ? stT : 0)) * I_ + stHalf * 16;
  unsigned short* aDstBase = As + stT * ASTR_ + stHalf * 16;

  // B fragment addressing (direct global; Wb is L2-resident)
  const int brow = h0 + w * 32 + (lane & 15);
  const int kcS  = (lane >> 4) * 8;
  const unsigned short* bBase0 = Wb + (size_t)brow * KP_ + kcS;
  const unsigned short* bBase1 = Wb + (size_t)(brow + 16) * KP_ + kcS;

  const int arow = lane & 15;

  f32x4 acc[7][2];
#pragma unroll
  for (int i = 0; i < 7; ++i) {
    acc[i][0] = f32x4{0.f, 0.f, 0.f, 0.f};
    acc[i][1] = f32x4{0.f, 0.f, 0.f, 0.f};
  }

  float4 aA0, aA1, aA2, aA3;   // prefetch set A (even k consume)
  float4 aB0, aB1, aB2, aB3;   // prefetch set B (odd k consume)
  short8v bC0, bC1, bN0, bN1;

  // ---- prologue: zero pad rows (both bufs); stage A(0); prime A(1),A(2),B ----
  if (stZr) {
    const uint4 z = {0, 0, 0, 0};
    *(uint4*)(aDstBase) = z;       *(uint4*)(aDstBase + 8) = z;
    *(uint4*)(aDstBase + TP_ * ASTR_) = z;
    *(uint4*)(aDstBase + TP_ * ASTR_ + 8) = z;
  }
  if (stLd) {
    aA0 = *(const float4*)(aBase + 0);
    aA1 = *(const float4*)(aBase + 4);
    aA2 = *(const float4*)(aBase + 8);
    aA3 = *(const float4*)(aBase + 12);
  }
  bC0 = *reinterpret_cast<const short8v*>(bBase0);
  bC1 = *reinterpret_cast<const short8v*>(bBase1);
  bN0 = *reinterpret_cast<const short8v*>(bBase0 + 32);
  bN1 = *reinterpret_cast<const short8v*>(bBase1 + 32);
  if (stLd) {
    const uint4 w0 = {cvtpk(aA0.x, aA0.y), cvtpk(aA0.z, aA0.w),
                      cvtpk(aA1.x, aA1.y), cvtpk(aA1.z, aA1.w)};
    const uint4 w1 = {cvtpk(aA2.x, aA2.y), cvtpk(aA2.z, aA2.w),
                      cvtpk(aA3.x, aA3.y), cvtpk(aA3.z, aA3.w)};
    *(uint4*)(aDstBase) = w0;
    *(uint4*)(aDstBase + 8) = w1;
    // prefetch A(1) -> set A, A(2) -> set B  (2-deep pipeline)
    aA0 = *(const float4*)(aBase + 32);
    aA1 = *(const float4*)(aBase + 36);
    aA2 = *(const float4*)(aBase + 40);
    aA3 = *(const float4*)(aBase + 44);
    aB0 = *(const float4*)(aBase + 64);
    aB1 = *(const float4*)(aBase + 68);
    aB2 = *(const float4*)(aBase + 72);
    aB3 = *(const float4*)(aBase + 76);
  }
  asm volatile("s_waitcnt lgkmcnt(0)" ::: "memory");
  __builtin_amdgcn_s_barrier();

  // STEP macro: k consumes LDS buf (k&1); stages A(k+1) from the given reg
  // set; reloads that set with A(k+3); B prefetched 1 ahead (L2-hot).
#define STEP(KV, R0, R1, R2, R3)                                               \
  {                                                                            \
    const int k = (KV);                                                        \
    const int buf  = (k & 1) * (TP_ * ASTR_);                                  \
    const int nbuf = ((k + 1) & 1) * (TP_ * ASTR_);                            \
    short8v a[7];                                                              \
    _Pragma("unroll")                                                          \
    for (int i = 0; i < 7; ++i)                                                \
      a[i] = *reinterpret_cast<const short8v*>(                                \
          As + buf + (arow + i * 16) * ASTR_ + kcS);                           \
    __builtin_amdgcn_s_setprio(1);                                             \
    _Pragma("unroll")                                                          \
    for (int i = 0; i < 7; ++i) {                                              \
      acc[i][0] = __builtin_amdgcn_mfma_f32_16x16x32_bf16(a[i], bC0, acc[i][0], 0, 0, 0); \
      acc[i][1] = __builtin_amdgcn_mfma_f32_16x16x32_bf16(a[i], bC1, acc[i][1], 0, 0, 0); \
    }                                                                          \
    __builtin_amdgcn_s_setprio(0);                                             \
    bC0 = bN0; bC1 = bN1;                                                      \
    if (k < 21 && stLd) {                                                      \
      const uint4 w0 = {cvtpk(R0.x, R0.y), cvtpk(R0.z, R0.w),                  \
                        cvtpk(R1.x, R1.y), cvtpk(R1.z, R1.w)};                 \
      const uint4 w1 = {cvtpk(R2.x, R2.y), cvtpk(R2.z, R2.w),                  \
                        cvtpk(R3.x, R3.y), cvtpk(R3.z, R3.w)};                 \
      *(uint4*)(aDstBase + nbuf) = w0;                                         \
      *(uint4*)(aDstBase + nbuf + 8) = w1;                                     \
    }                                                                          \
    if (k <= 18 && stLd) {                                                     \
      const int kn  = k + 3;                                                   \
      const int phn = (kn >= 11);                                              \
      const int offn = phn ? 348 : 0;                                          \
      const int k0n  = (kn - phn * 11) * 32;                                   \
      const float* ap = aBase + offn + k0n;                                    \
      R0 = *(const float4*)(ap + 0);                                           \
      R1 = *(const float4*)(ap + 4);                                           \
      R2 = *(const float4*)(ap + 8);                                           \
      R3 = *(const float4*)(ap + 12);                                          \
    }                                                                          \
    if (k < 20) {                                                              \
      const int kb  = k + 2;                                                   \
      const int phb = (kb >= 11);                                              \
      const size_t bo = (size_t)phb * H_ * KP_ + (kb - phb * 11) * 32;         \
      bN0 = *reinterpret_cast<const short8v*>(bBase0 + bo);                    \
      bN1 = *reinterpret_cast<const short8v*>(bBase1 + bo);                    \
    }                                                                          \
    if (k == 10 || k == 21) {                                                  \
      unsigned short* ds = (k == 10) ? d1s : d2s;                              \
      _Pragma("unroll")                                                        \
      for (int i = 0; i < 7; ++i) {                                            \
        const int tb = i * 16 + ((lane >> 4) << 2);                            \
        _Pragma("unroll")                                                      \
        for (int j = 0; j < 2; ++j) {                                          \
          const int hl = w * 32 + j * 16 + (lane & 15);                        \
          const uint2 pk = {cvtpk(acc[i][j][0], acc[i][j][1]),                 \
                            cvtpk(acc[i][j][2], acc[i][j][3])};                \
          *(uint2*)(ds + hl * DRS_ + tb) = pk;                                 \
          acc[i][j] = f32x4{0.f, 0.f, 0.f, 0.f};                               \
        }                                                                      \
      }                                                                        \
    }                                                                          \
    asm volatile("s_waitcnt lgkmcnt(0)" ::: "memory");                         \
    __builtin_amdgcn_s_barrier();                                              \
  }

#pragma unroll 1
  for (int kk = 0; kk < 11; ++kk) {
    STEP(2 * kk,     aA0, aA1, aA2, aA3);
    STEP(2 * kk + 1, aB0, aB1, aB2, aB3);
  }
#undef STEP

  // ---- in-block LIF scan: thread = one h column ----
  if (tid < 128) {
    const int hg = h0 + tid;
    const float beta1 = sigmoidf_(tau_n[hg]);
    const float beta2 = sigmoidf_(tau_n[H_ + hg]);
    const float alpha = sigmoidf_(tau_m[hg]);
    const float ob1 = 1.0f - beta1, ob2 = 1.0f - beta2, oa = 1.0f - alpha;

    float d1 = 0.0f, d2 = 0.0f, s = 0.0f;
    float v = v_init[(size_t)b * H_ + hg];
    const unsigned short* r1 = d1s + tid * DRS_;
    const unsigned short* r2 = d2s + tid * DRS_;
    unsigned char* sp = spikes + (size_t)b * H_ + hg;
#pragma unroll 1
    for (int c = 0; c < 25; ++c) {                    // 25 x 4 = 100 steps
      const uint2 x1 = *(const uint2*)(r1 + c * 4);
      const uint2 x2 = *(const uint2*)(r2 + c * 4);
      const unsigned u1[2] = {x1.x, x1.y};
      const unsigned u2[2] = {x2.x, x2.y};
#pragma unroll
      for (int j = 0; j < 4; ++j) {
        const unsigned w1u = u1[j >> 1], w2u = u2[j >> 1];
        const float f1 = (j & 1) ? __uint_as_float(w1u & 0xffff0000u)
                                 : __uint_as_float(w1u << 16);
        const float f2 = (j & 1) ? __uint_as_float(w2u & 0xffff0000u)
                                 : __uint_as_float(w2u << 16);
        d1 = beta1 * d1 + ob1 * f1;
        d2 = beta2 * d2 + ob2 * f2;
        v = alpha * v + oa * (d1 + d2) - s;   // V_TH = 1
        s = (v > 1.0f) ? 1.0f : 0.0f;
        sp[(size_t)(c * 4 + j) * BH_] = (unsigned char)s;
      }
    }
  }
}

// ---------- fused output GEMM + loss partials (wave per (b,t)) ----------
__global__ __launch_bounds__(256) void out_loss(
    const unsigned char* __restrict__ spikes, const float* __restrict__ Wout,
    const float* __restrict__ bout, const int* __restrict__ target,
    float* __restrict__ oh, float* __restrict__ partials)
{
  const int lane = threadIdx.x & 63;
  const int widx = threadIdx.x >> 6;
  const int bt = blockIdx.x * 4 + widx;
  const int b = bt / T_, t = bt - b * T_;

  const unsigned char* srow = spikes + ((size_t)t * B_ + b) * H_;
  const uint2 sv = *(const uint2*)(srow + lane * 8);

  float acc[O_];
#pragma unroll
  for (int o = 0; o < O_; ++o) acc[o] = 0.0f;

#pragma unroll
  for (int j = 0; j < 8; ++j) {
    const unsigned sb = ((j < 4) ? (sv.x >> (8 * j)) : (sv.y >> (8 * (j - 4)))) & 255u;
    if (sb) {
      const int hh = lane * 8 + j;
#pragma unroll
      for (int o = 0; o < O_; ++o) acc[o] += Wout[o * H_ + hh];
    }
  }
#pragma unroll
  for (int o = 0; o < O_; ++o) {
#pragma unroll
    for (int off = 32; off > 0; off >>= 1) acc[o] += __shfl_down(acc[o], off);
  }

  __shared__ float sl[4], sc[4];
  if (lane == 0) {
    float r[O_];
    float* orow = oh + ((size_t)b * T_ + t) * O_;
#pragma unroll
    for (int o = 0; o < O_; ++o) { r[o] = acc[o] + bout[o]; orow[o] = r[o]; }

    float lossc = 0.0f, corr = 0.0f;
    const bool maskv = (t > START_T) && (((t - START_T) % (CODING_T + REMAIN_T)) > REMAIN_T);
    if (maskv) {
      float m = r[0];
#pragma unroll
      for (int o = 1; o < O_; ++o) m = fmaxf(m, r[o]);
      const int tgt = target[(size_t)b * T_ + t];
      float e[O_], S = 0.0f, etgt = 0.0f;
#pragma unroll
      for (int o = 0; o < O_; ++o) {
        e[o] = expf(r[o] - m);
        S += e[o];
        etgt = (o == tgt) ? e[o] : etgt;
      }
      const float inv = 1.0f / S;
      const float pm = inv;            // max(p) = exp(0)/S
      float S2 = 0.0f;
#pragma unroll
      for (int o = 0; o < O_; ++o) S2 += expf(e[o] * inv - pm);
      const float lse = pm + logf(S2);
      lossc = (lse - etgt * inv) * (1.0f / (float)B_);
      int pred = 0;
      float bm = r[0];
#pragma unroll
      for (int o = 1; o < O_; ++o) { if (r[o] > bm) { bm = r[o]; pred = o; } }
      corr = (pred == tgt) ? 1.0f : 0.0f;
    }
    sl[widx] = lossc; sc[widx] = corr;
  }
  __syncthreads();
  if (threadIdx.x == 0) {
    partials[blockIdx.x]       = sl[0] + sl[1] + sl[2] + sl[3];
    partials[NB_ + blockIdx.x] = sc[0] + sc[1] + sc[2] + sc[3];
  }
}

__global__ __launch_bounds__(256) void loss_final(
    const float* __restrict__ partials, float* __restrict__ out, float samples)
{
  float a = 0.0f, c = 0.0f;
  for (int i = threadIdx.x; i < NB_; i += 256) { a += partials[i]; c += partials[NB_ + i]; }
  __shared__ float sl[256], sc[256];
  sl[threadIdx.x] = a; sc[threadIdx.x] = c;
  __syncthreads();
  for (int s = 128; s > 0; s >>= 1) {
    if (threadIdx.x < s) {
      sl[threadIdx.x] += sl[threadIdx.x + s];
      sc[threadIdx.x] += sc[threadIdx.x + s];
    }
    __syncthreads();
  }
  if (threadIdx.x == 0) {
    out[0] = sl[0];
    out[1 + (size_t)M_ * O_] = sc[0];
    out[2 + (size_t)M_ * O_] = samples;
  }
}

extern "C" void kernel_launch(void* const* d_in, const int* in_sizes, int n_in,
                              void* d_out, int out_size, void* d_ws, size_t ws_size,
                              hipStream_t stream) {
  const float* input  = (const float*)d_in[0];
  const int*   target = (const int*)d_in[1];
  const float* v_init = (const float*)d_in[2];
  const float* W1     = (const float*)d_in[3];
  const float* W2     = (const float*)d_in[4];
  const float* tau_n  = (const float*)d_in[5];
  const float* tau_m  = (const float*)d_in[6];
  const float* Wout   = (const float*)d_in[7];
  const float* bout   = (const float*)d_in[8];
  float* out = (float*)d_out;
  float* oh  = out + 1;

  // ws layout: Wb[2*512*352 bf16] spikes[T*BH u8] partials[2*NB_ f32]
  unsigned short* Wb = (unsigned short*)d_ws;
  unsigned char* spikes = (unsigned char*)(Wb + (size_t)2 * H_ * KP_);
  float* partials = (float*)(spikes + (size_t)T_ * BH_);

  const dim3 blk(256);

  hipLaunchKernelGGL(convert_w, dim3((2 * H_ * KP_ / 8) / 256), blk, 0, stream,
                     W1, W2, Wb);

  hipLaunchKernelGGL(fused_drive_scan, dim3(2000), blk, 0, stream,
                     input, Wb, v_init, tau_n, tau_m, spikes);

  hipLaunchKernelGGL(out_loss, dim3(NB_), blk, 0, stream,
                     spikes, Wout, bout, target, oh, partials);

  int mcount = 0;
  for (int t = 0; t < T_; ++t)
    if (t > START_T && ((t - START_T) % (CODING_T + REMAIN_T)) > REMAIN_T) mcount++;
  hipLaunchKernelGGL(loss_final, dim3(1), blk, 0, stream, partials,
                     out, (float)(mcount * B_));
}

// Round 9
// 164.944 us; speedup vs baseline: 4.1670x; 1.2707x over previous
//
#include <hip/hip_runtime.h>
#include <hip/hip_bf16.h>
#include <math.h>

#define B_    500
#define T_    100
#define I_    700
#define HALF_ 350
#define H_    512
#define O_    20
#define M_    (B_*T_)     // 50000
#define BH_   (B_*H_)     // 256000
#define TP_   112         // T padded to 7*16
#define KP_   352         // padded K per phase
#define ASTR_ 40          // A LDS row stride shorts (80B)
#define ABUF_ (TP_*ASTR_) // 4480 shorts per A buffer
#define DRB_  116         // dr LDS t-stride BYTES (4-aligned, 29 dwords: conflict-free)
#define NB_   12500       // out_loss blocks

#define START_T  10
#define CODING_T 10
#define REMAIN_T 5

typedef __attribute__((ext_vector_type(8))) short short8v;
typedef __attribute__((ext_vector_type(8))) unsigned short ushort8v;
typedef __attribute__((ext_vector_type(4))) float f32x4;
typedef __attribute__((ext_vector_type(2))) float f32x2;

__device__ __forceinline__ float sigmoidf_(float x) {
  return 1.0f / (1.0f + expf(-x));
}

// HW packed cvt f32x2 -> 2 bf16 (RTNE)
__device__ __forceinline__ unsigned cvtpk(float lo, float hi) {
  unsigned r;
  asm("v_cvt_pk_bf16_f32 %0, %1, %2" : "=v"(r) : "v"(lo), "v"(hi));
  return r;
}

// HW packed cvt 4 f32 -> 4 fp8 e4m3 bytes (t-order), via builtins
__device__ __forceinline__ unsigned cvtpk_fp8x4(float f0, float f1, float f2, float f3) {
  int r = __builtin_amdgcn_cvt_pk_fp8_f32(f0, f1, 0, false);   // bytes 0,1
  r = __builtin_amdgcn_cvt_pk_fp8_f32(f2, f3, r, true);        // bytes 2,3
  return (unsigned)r;
}

__device__ __forceinline__ unsigned short f2bf(float f) {
  unsigned u = __float_as_uint(f);
  u = (u + 0x7fffu + ((u >> 16) & 1u)) >> 16;   // RTNE
  return (unsigned short)u;
}

// ---------- convert weights fp32 -> padded bf16 Wb[2][512][352] ----------
// phase 0: kk<350 -> W1[kk], else 0      (A cols 0..351)
// phase 1: kk>=2  -> W2[kk-2], else 0    (A cols 348..699; 16B-aligned base)
__global__ __launch_bounds__(256) void convert_w(
    const float* __restrict__ W1, const float* __restrict__ W2,
    unsigned short* __restrict__ wb)
{
  const int idx = blockIdx.x * 256 + threadIdx.x;  // 8-elem chunk; 45056 total
  const int ph  = idx / (H_ * (KP_ / 8));
  const int rem = idx % (H_ * (KP_ / 8));
  const int h   = rem / (KP_ / 8);
  const int cc  = (rem % (KP_ / 8)) * 8;
  ushort8v v;
#pragma unroll
  for (int j = 0; j < 8; ++j) {
    const int kk = cc + j;
    float f;
    if (ph == 0) f = (kk < HALF_) ? W1[(size_t)h * HALF_ + kk] : 0.0f;
    else         f = (kk >= 2)    ? W2[(size_t)h * HALF_ + kk - 2] : 0.0f;
    v[j] = f2bf(f);
  }
  *reinterpret_cast<ushort8v*>(wb + (((size_t)ph * H_ + h) * KP_) + cc) = v;
}

// ---------- fused: per-b drive GEMM (all 512 h) + in-LDS LIF scan ----------
// 1024 threads = 16 waves, one block per b. dr stored as fp8 e4m3 in LDS.
__global__ __launch_bounds__(1024, 4) void fused_drive_scan(
    const float* __restrict__ input, const unsigned short* __restrict__ Wb,
    const float* __restrict__ v_init, const float* __restrict__ tau_n,
    const float* __restrict__ tau_m, unsigned char* __restrict__ spikes)
{
  __shared__ __align__(16) unsigned short As[2 * ABUF_];   // 17920 B
  __shared__ __align__(4) unsigned char d1c[H_ * DRB_];    // 59392 B (fp8)
  __shared__ __align__(4) unsigned char d2c[H_ * DRB_];    // 59392 B (fp8)

  const int tid  = threadIdx.x;
  const int lane = tid & 63;
  const int w    = tid >> 6;           // 0..15
  const int b    = blockIdx.x;         // 0..499

  // A staging: thread tid<896 -> row sr = tid>>3, 4-float chunk so = (tid&7)*4
  const int sr = tid >> 3;
  const int so = (tid & 7) * 4;
  const bool stLd = (tid < 800);                    // sr < 100
  const bool stZr = (tid >= 800) && (tid < 896);    // pad rows 100..111
  const float* aBase = input + ((size_t)b * T_ + (stLd ? sr : 0)) * I_ + so;
  unsigned short* aDst = As + sr * ASTR_ + so;

  // B fragment addressing (direct global; Wb is L2-resident)
  const int brow = w * 32 + (lane & 15);
  const int kcS  = (lane >> 4) * 8;
  const unsigned short* bBase0 = Wb + (size_t)brow * KP_ + kcS;
  const unsigned short* bBase1 = Wb + (size_t)(brow + 16) * KP_ + kcS;
  const int arow = lane & 15;

  f32x4 acc[7][2];
#pragma unroll
  for (int i = 0; i < 7; ++i) {
    acc[i][0] = f32x4{0.f, 0.f, 0.f, 0.f};
    acc[i][1] = f32x4{0.f, 0.f, 0.f, 0.f};
  }

  float4 aR;
  short8v bC0, bC1, bN0, bN1;

  // ---- prologue: zero pad rows (both bufs); stage A(0); prefetch A(1), B ----
  if (stZr) {
    const uint2 z = {0, 0};
    *(uint2*)(aDst) = z;
    *(uint2*)(aDst + ABUF_) = z;
  }
  if (stLd) aR = *(const float4*)(aBase);
  bC0 = *reinterpret_cast<const short8v*>(bBase0);
  bC1 = *reinterpret_cast<const short8v*>(bBase1);
  bN0 = *reinterpret_cast<const short8v*>(bBase0 + 32);
  bN1 = *reinterpret_cast<const short8v*>(bBase1 + 32);
  if (stLd) {
    const uint2 p = {cvtpk(aR.x, aR.y), cvtpk(aR.z, aR.w)};
    *(uint2*)(aDst) = p;
    aR = *(const float4*)(aBase + 32);   // A(1)
  }
  asm volatile("s_waitcnt lgkmcnt(0)" ::: "memory");
  __builtin_amdgcn_s_barrier();
  asm volatile("" ::: "memory");

#pragma unroll 1
  for (int k = 0; k < 22; ++k) {
    const int buf  = (k & 1) * ABUF_;
    const int nbuf = ((k + 1) & 1) * ABUF_;
    // ---- A fragments + MFMA ----
    short8v a[7];
#pragma unroll
    for (int i = 0; i < 7; ++i)
      a[i] = *reinterpret_cast<const short8v*>(As + buf + (arow + i * 16) * ASTR_ + kcS);
#pragma unroll
    for (int i = 0; i < 7; ++i) {
      acc[i][0] = __builtin_amdgcn_mfma_f32_16x16x32_bf16(a[i], bC0, acc[i][0], 0, 0, 0);
      acc[i][1] = __builtin_amdgcn_mfma_f32_16x16x32_bf16(a[i], bC1, acc[i][1], 0, 0, 0);
    }
    bC0 = bN0; bC1 = bN1;
    // ---- stage A(k+1) from in-flight aR; prefetch A(k+2), B(k+2) ----
    if (k < 21 && stLd) {
      const uint2 p = {cvtpk(aR.x, aR.y), cvtpk(aR.z, aR.w)};
      *(uint2*)(aDst + nbuf) = p;
    }
    if (k < 20 && stLd) {
      const int kn  = k + 2;
      const int ph  = (kn >= 11);
      const int k0  = (kn - ph * 11) * 32;
      aR = *(const float4*)(aBase + (ph ? 348 : 0) + k0);
    }
    if (k < 20) {
      const int kb  = k + 2;
      const int phb = (kb >= 11);
      const size_t bo = (size_t)phb * H_ * KP_ + (kb - phb * 11) * 32;
      bN0 = *reinterpret_cast<const short8v*>(bBase0 + bo);
      bN1 = *reinterpret_cast<const short8v*>(bBase1 + bo);
    }
    // ---- phase boundary: dump acc -> fp8 dr LDS, reset ----
    if (k == 10 || k == 21) {
      unsigned char* ds = (k == 10) ? d1c : d2c;
#pragma unroll
      for (int i = 0; i < 7; ++i) {
        const int tb = i * 16 + ((lane >> 4) << 2);
#pragma unroll
        for (int j = 0; j < 2; ++j) {
          const int hl = w * 32 + j * 16 + (lane & 15);
          const unsigned r =
              cvtpk_fp8x4(acc[i][j][0], acc[i][j][1], acc[i][j][2], acc[i][j][3]);
          *(unsigned*)(ds + hl * DRB_ + tb) = r;
          acc[i][j] = f32x4{0.f, 0.f, 0.f, 0.f};
        }
      }
    }
    asm volatile("s_waitcnt lgkmcnt(0)" ::: "memory");
    __builtin_amdgcn_s_barrier();
    asm volatile("" ::: "memory");
  }

  // ---- in-block LIF scan: thread = one h column (waves 0-7) ----
  if (tid < H_) {
    const int hg = tid;
    const float beta1 = sigmoidf_(tau_n[hg]);
    const float beta2 = sigmoidf_(tau_n[H_ + hg]);
    const float alpha = sigmoidf_(tau_m[hg]);
    const float ob1 = 1.0f - beta1, ob2 = 1.0f - beta2, oa = 1.0f - alpha;

    float d1 = 0.0f, d2 = 0.0f, s = 0.0f;
    float v = v_init[(size_t)b * H_ + hg];
    const unsigned char* r1 = d1c + hg * DRB_;
    const unsigned char* r2 = d2c + hg * DRB_;
    unsigned char* sp = spikes + (size_t)b * H_ + hg;
#pragma unroll 1
    for (int c = 0; c < 25; ++c) {                    // 25 x 4 = 100 steps
      const unsigned u1 = *(const unsigned*)(r1 + c * 4);
      const unsigned u2 = *(const unsigned*)(r2 + c * 4);
      const f32x2 a1 = __builtin_amdgcn_cvt_pk_f32_fp8((int)u1, false);
      const f32x2 b1 = __builtin_amdgcn_cvt_pk_f32_fp8((int)u1, true);
      const f32x2 a2 = __builtin_amdgcn_cvt_pk_f32_fp8((int)u2, false);
      const f32x2 b2 = __builtin_amdgcn_cvt_pk_f32_fp8((int)u2, true);
      const float f1[4] = {a1[0], a1[1], b1[0], b1[1]};
      const float f2[4] = {a2[0], a2[1], b2[0], b2[1]};
#pragma unroll
      for (int j = 0; j < 4; ++j) {
        d1 = beta1 * d1 + ob1 * f1[j];
        d2 = beta2 * d2 + ob2 * f2[j];
        v = alpha * v + oa * (d1 + d2) - s;   // V_TH = 1
        s = (v > 1.0f) ? 1.0f : 0.0f;
        sp[(size_t)(c * 4 + j) * BH_] = (unsigned char)s;
      }
    }
  }
}

// ---------- fused output GEMM + loss partials (wave per (b,t)) ----------
__global__ __launch_bounds__(256) void out_loss(
    const unsigned char* __restrict__ spikes, const float* __restrict__ Wout,
    const float* __restrict__ bout, const int* __restrict__ target,
    float* __restrict__ oh, float* __restrict__ partials)
{
  const int lane = threadIdx.x & 63;
  const int widx = threadIdx.x >> 6;
  const int bt = blockIdx.x * 4 + widx;
  const int b = bt / T_, t = bt - b * T_;

  const unsigned char* srow = spikes + ((size_t)t * B_ + b) * H_;
  const uint2 sv = *(const uint2*)(srow + lane * 8);

  float acc[O_];
#pragma unroll
  for (int o = 0; o < O_; ++o) acc[o] = 0.0f;

#pragma unroll
  for (int j = 0; j < 8; ++j) {
    const unsigned sb = ((j < 4) ? (sv.x >> (8 * j)) : (sv.y >> (8 * (j - 4)))) & 255u;
    if (sb) {
      const int hh = lane * 8 + j;
#pragma unroll
      for (int o = 0; o < O_; ++o) acc[o] += Wout[o * H_ + hh];
    }
  }
#pragma unroll
  for (int o = 0; o < O_; ++o) {
#pragma unroll
    for (int off = 32; off > 0; off >>= 1) acc[o] += __shfl_down(acc[o], off);
  }

  __shared__ float sl[4], sc[4];
  if (lane == 0) {
    float r[O_];
    float* orow = oh + ((size_t)b * T_ + t) * O_;
#pragma unroll
    for (int o = 0; o < O_; ++o) { r[o] = acc[o] + bout[o]; orow[o] = r[o]; }

    float lossc = 0.0f, corr = 0.0f;
    const bool maskv = (t > START_T) && (((t - START_T) % (CODING_T + REMAIN_T)) > REMAIN_T);
    if (maskv) {
      float m = r[0];
#pragma unroll
      for (int o = 1; o < O_; ++o) m = fmaxf(m, r[o]);
      const int tgt = target[(size_t)b * T_ + t];
      float e[O_], S = 0.0f, etgt = 0.0f;
#pragma unroll
      for (int o = 0; o < O_; ++o) {
        e[o] = expf(r[o] - m);
        S += e[o];
        etgt = (o == tgt) ? e[o] : etgt;
      }
      const float inv = 1.0f / S;
      const float pm = inv;            // max(p) = exp(0)/S
      float S2 = 0.0f;
#pragma unroll
      for (int o = 0; o < O_; ++o) S2 += expf(e[o] * inv - pm);
      const float lse = pm + logf(S2);
      lossc = (lse - etgt * inv) * (1.0f / (float)B_);
      int pred = 0;
      float bm = r[0];
#pragma unroll
      for (int o = 1; o < O_; ++o) { if (r[o] > bm) { bm = r[o]; pred = o; } }
      corr = (pred == tgt) ? 1.0f : 0.0f;
    }
    sl[widx] = lossc; sc[widx] = corr;
  }
  __syncthreads();
  if (threadIdx.x == 0) {
    partials[blockIdx.x]       = sl[0] + sl[1] + sl[2] + sl[3];
    partials[NB_ + blockIdx.x] = sc[0] + sc[1] + sc[2] + sc[3];
  }
}

__global__ __launch_bounds__(256) void loss_final(
    const float* __restrict__ partials, float* __restrict__ out, float samples)
{
  float a = 0.0f, c = 0.0f;
  for (int i = threadIdx.x; i < NB_; i += 256) { a += partials[i]; c += partials[NB_ + i]; }
  __shared__ float sl[256], sc[256];
  sl[threadIdx.x] = a; sc[threadIdx.x] = c;
  __syncthreads();
  for (int s = 128; s > 0; s >>= 1) {
    if (threadIdx.x < s) {
      sl[threadIdx.x] += sl[threadIdx.x + s];
      sc[threadIdx.x] += sc[threadIdx.x + s];
    }
    __syncthreads();
  }
  if (threadIdx.x == 0) {
    out[0] = sl[0];
    out[1 + (size_t)M_ * O_] = sc[0];
    out[2 + (size_t)M_ * O_] = samples;
  }
}

extern "C" void kernel_launch(void* const* d_in, const int* in_sizes, int n_in,
                              void* d_out, int out_size, void* d_ws, size_t ws_size,
                              hipStream_t stream) {
  const float* input  = (const float*)d_in[0];
  const int*   target = (const int*)d_in[1];
  const float* v_init = (const float*)d_in[2];
  const float* W1     = (const float*)d_in[3];
  const float* W2     = (const float*)d_in[4];
  const float* tau_n  = (const float*)d_in[5];
  const float* tau_m  = (const float*)d_in[6];
  const float* Wout   = (const float*)d_in[7];
  const float* bout   = (const float*)d_in[8];
  float* out = (float*)d_out;
  float* oh  = out + 1;

  // ws layout: Wb[2*512*352 bf16] spikes[T*BH u8] partials[2*NB_ f32]
  unsigned short* Wb = (unsigned short*)d_ws;
  unsigned char* spikes = (unsigned char*)(Wb + (size_t)2 * H_ * KP_);
  float* partials = (float*)(spikes + (size_t)T_ * BH_);

  hipLaunchKernelGGL(convert_w, dim3((2 * H_ * KP_ / 8) / 256), dim3(256), 0, stream,
                     W1, W2, Wb);

  hipLaunchKernelGGL(fused_drive_scan, dim3(B_), dim3(1024), 0, stream,
                     input, Wb, v_init, tau_n, tau_m, spikes);

  hipLaunchKernelGGL(out_loss, dim3(NB_), dim3(256), 0, stream,
                     spikes, Wout, bout, target, oh, partials);

  int mcount = 0;
  for (int t = 0; t < T_; ++t)
    if (t > START_T && ((t - START_T) % (CODING_T + REMAIN_T)) > REMAIN_T) mcount++;
  hipLaunchKernelGGL(loss_final, dim3(1), dim3(256), 0, stream, partials,
                     out, (float)(mcount * B_));
}